// Round 5
// baseline (229.139 us; speedup 1.0000x reference)
//
#include <hip/hip_runtime.h>
#include <hip/hip_bf16.h>

// Problem shapes (fixed by setup_inputs)
constexpr int B_  = 4;
constexpr int N_  = 2048;
constexpr int C_  = 1024;
constexpr int H_  = 16;
constexpr int HD  = 64;    // head dim
constexpr int LR  = 20;    // low rank
constexpr int RS  = 200;   // subsample length R
constexpr int RP  = 224;   // RS padded to multiple of 32 (zero-filled)

typedef __attribute__((ext_vector_type(8))) short bf16x8;
typedef __attribute__((ext_vector_type(4))) float f32x4;

__device__ __forceinline__ float b2f_raw(unsigned short u) {
    union { unsigned int i; float f; } v;
    v.i = ((unsigned int)u) << 16;
    return v.f;
}
__device__ __forceinline__ unsigned short f2b(float f) {
    __hip_bfloat16 h = __float2bfloat16(f);
    return *(unsigned short*)&h;
}
template <bool BF>
__device__ __forceinline__ float ldg(const void* p, size_t i) {
    if constexpr (BF) return b2f_raw(((const unsigned short*)p)[i]);
    else              return ((const float*)p)[i];
}

// async 16B global->LDS (wave-uniform LDS base; HW scatters lane i at +16*i)
__device__ __forceinline__ void async_load16(const unsigned short* g, unsigned short* l) {
    __builtin_amdgcn_global_load_lds(
        (const __attribute__((address_space(1))) unsigned int*)(const void*)g,
        (__attribute__((address_space(3))) unsigned int*)(void*)l,
        16, 0, 0);
}

// ---------------------------------------------------------------------------
// Inline dtype detect (replaces the detect kernel -> one less launch).
// Deterministic function of x[0..1023] (same criterion as the old kernel),
// so every block in every kernel computes the SAME verdict. Wave-uniform:
// each lane reads 16 contiguous dwords, wave-reduce via shfl_xor. ~4KB read,
// L1/L2-hot after the first wave; cost << 1 us.
// ---------------------------------------------------------------------------
__device__ __forceinline__ bool detect_bf16(const unsigned int* __restrict__ x) {
    const int lane = threadIdx.x & 63;
    int cnt = 0;
    #pragma unroll
    for (int i = 0; i < 16; ++i) {
        const unsigned int w = x[lane * 16 + i];
        const unsigned int e = (w >> 7) & 0xFFu;
        cnt += (e >= 103u && e <= 140u) ? 1 : 0;
    }
    #pragma unroll
    for (int s = 1; s < 64; s <<= 1) cnt += __shfl_xor(cnt, s, 64);
    return cnt > 512;
}

// ---------------------------------------------------------------------------
// Fused convert + wec + gather. Grid (2048, 7):
//  y in [0,5): convert buffer y (x, qkw, proj_w, proj_b, cw_b) to bf16
//             -- SKIPPED entirely when inputs are bf16 (zero-copy: consumers
//                read the raw buffers directly; bit-identical).
//  y == 5:    wec from RAW we/wr/cw_w: wect[h][dout][r] = sum_e we*cw
//  y == 6:    gather from RAW x: xh[bh][din][r] = x[b, idx[r], h*64+din]
// idx[r] = (r*(N-1))/(R-1) exactly (trunc linspace); r zero-padded to 224.
// ---------------------------------------------------------------------------
struct CvtArgs {
    const void* src[5];
    unsigned short* dst[5];
    int size[5];
};

template <bool BF>
__device__ void wec_body(const void* __restrict__ we_raw,
                         const void* __restrict__ wr_raw,
                         const void* __restrict__ cw_raw,
                         unsigned short* __restrict__ wect,
                         unsigned short* __restrict__ wrct) {
    const int o = blockIdx.x * 256 + threadIdx.x;
    if (o >= H_ * HD * RP) return;
    const int r    = o % RP;
    const int dout = (o / RP) % HD;
    const int h    = o / (RP * HD);
    float sq = 0.f, sk = 0.f;
    if (r < RS) {
        #pragma unroll
        for (int e = 0; e < LR; ++e) {
            const float cq = ldg<BF>(cw_raw, dout * 2 * LR + e);
            const float ck = ldg<BF>(cw_raw, dout * 2 * LR + LR + e);
            sq += ldg<BF>(we_raw, ((size_t)h * RS + r) * LR + e) * cq;
            sk += ldg<BF>(wr_raw, ((size_t)h * RS + r) * LR + e) * ck;
        }
    }
    wect[o] = f2b(sq);
    wrct[o] = f2b(sk);
}

template <bool BF>
__device__ void gather_body(const void* __restrict__ x_raw,
                            unsigned short* __restrict__ xh) {
    const int bh = blockIdx.x;
    if (bh >= B_ * H_) return;
    const int b = bh >> 4;
    const int h = bh & 15;
    for (int o = threadIdx.x; o < HD * RP; o += 256) {
        const int din = o & 63;   // consecutive threads -> coalesced reads
        const int r   = o >> 6;
        unsigned short v = 0;
        if (r < RS) {
            const int ir = (r * (N_ - 1)) / (RS - 1);
            const size_t idx = ((size_t)b * N_ + ir) * C_ + h * HD + din;
            if constexpr (BF) v = ((const unsigned short*)x_raw)[idx];
            else              v = f2b(((const float*)x_raw)[idx]);
        }
        xh[(size_t)bh * HD * RP + (size_t)din * RP + r] = v;
    }
}

__global__ __launch_bounds__(256)
void fused_prep_kernel(CvtArgs args,
                       const void* __restrict__ we_raw,
                       const void* __restrict__ wr_raw,
                       const void* __restrict__ cw_raw,
                       unsigned short* __restrict__ wect,
                       unsigned short* __restrict__ wrct,
                       unsigned short* __restrict__ xh) {
    const bool isbf = detect_bf16((const unsigned int*)args.src[0]);
    const int y = blockIdx.y;
    if (y < 5) {
        if (isbf) return;   // zero-copy path: raw buffers are already bf16
        const int n4 = args.size[y] >> 2;
        const int stride = gridDim.x * blockDim.x;
        for (int i = blockIdx.x * blockDim.x + threadIdx.x; i < n4; i += stride) {
            const float4 v = ((const float4*)args.src[y])[i];
            ushort4 o;
            o.x = f2b(v.x); o.y = f2b(v.y); o.z = f2b(v.z); o.w = f2b(v.w);
            ((ushort4*)args.dst[y])[i] = o;
        }
    } else if (y == 5) {
        if (isbf) wec_body<true>(we_raw, wr_raw, cw_raw, wect, wrct);
        else      wec_body<false>(we_raw, wr_raw, cw_raw, wect, wrct);
    } else {
        if (isbf) gather_body<true>(args.src[0], xh);
        else      gather_body<false>(args.src[0], xh);
    }
}

// ---------------------------------------------------------------------------
// collapse: We2T[bh][dout][din] = sum_r wec[h][dout][r] * xh[bh][din][r]
// Tiny NT MFMA GEMM, M=N=64, K=224. One wave per (bh, qk-sel, dout-half).
// (verified in rounds 5-8 of the previous session; unchanged)
// ---------------------------------------------------------------------------
__global__ __launch_bounds__(64)
void collapse_kernel(const unsigned short* __restrict__ xh,
                     const unsigned short* __restrict__ wect,
                     const unsigned short* __restrict__ wrct,
                     unsigned short* __restrict__ we2t,
                     unsigned short* __restrict__ wr2t) {
    const int blk = blockIdx.x;
    const int bh  = blk >> 2;
    const int qk  = (blk >> 1) & 1;
    const int dh  = blk & 1;
    const int h   = bh & 15;
    const int lane = threadIdx.x;
    const int lq = lane >> 4;
    const int lm = lane & 15;

    const unsigned short* wsrc = (qk ? wrct : wect) + (size_t)h * HD * RP;
    const unsigned short* xsrc = xh + (size_t)bh * HD * RP;
    unsigned short* dst = (qk ? wr2t : we2t) + (size_t)bh * HD * HD;

    f32x4 acc[2][4];
    #pragma unroll
    for (int i = 0; i < 2; ++i)
        #pragma unroll
        for (int j = 0; j < 4; ++j) acc[i][j] = 0.f;

    for (int ks = 0; ks < RP / 32; ++ks) {
        bf16x8 a[2], bfr[4];
        #pragma unroll
        for (int rt = 0; rt < 2; ++rt)
            a[rt] = *(const bf16x8*)&wsrc[(size_t)(dh * 32 + rt * 16 + lm) * RP + ks * 32 + lq * 8];
        #pragma unroll
        for (int j = 0; j < 4; ++j)
            bfr[j] = *(const bf16x8*)&xsrc[(size_t)(j * 16 + lm) * RP + ks * 32 + lq * 8];
        #pragma unroll
        for (int rt = 0; rt < 2; ++rt)
            #pragma unroll
            for (int j = 0; j < 4; ++j)
                acc[rt][j] = __builtin_amdgcn_mfma_f32_16x16x32_bf16(
                    a[rt], bfr[j], acc[rt][j], 0, 0, 0);
    }

    #pragma unroll
    for (int rt = 0; rt < 2; ++rt)
        #pragma unroll
        for (int j = 0; j < 4; ++j)
            #pragma unroll
            for (int r = 0; r < 4; ++r) {
                const int dout = dh * 32 + rt * 16 + lq * 4 + r;
                const int din  = j * 16 + lm;
                dst[dout * HD + din] = f2b(acc[rt][j][r]);
            }
}

// ---------------------------------------------------------------------------
// Fused gemm1 + l2norm + score. Body identical to round 4 (BK=64 dbuf,
// T3-minimum recipe, both-sides swizzle). NEW this round:
//  - inline detect + raw-pointer select (bf16 zero-copy)
//  - T1 XCD-chunked block swizzle: logical = (lin&7)*128 + (lin>>3), so each
//    XCD owns 8 contiguous m-panels x 16 h -> A-panel fetched on exactly one
//    XCD (FETCH_SIZE predicted 70 -> ~50 MB).
// ---------------------------------------------------------------------------
__global__ __launch_bounds__(256, 2)
void gemm1_score_kernel(const void* __restrict__ x_raw,
                        const void* __restrict__ qkw_raw,
                        const void* __restrict__ cwb_raw,
                        const unsigned short* __restrict__ xb,
                        const unsigned short* __restrict__ qkwb,
                        const unsigned short* __restrict__ cwbb,
                        const unsigned short* __restrict__ we2t,
                        const unsigned short* __restrict__ wr2t,
                        unsigned short* __restrict__ attn) {
    constexpr int QS = 72;
    __shared__ __align__(16) unsigned short pool[32768];  // 64 KB
    unsigned short* const AsBase = pool;          // 2 x 128x64 A tiles (32 KB)
    unsigned short* const BsBase = pool + 16384;  // 2 x 128x64 B tiles (32 KB)
    unsigned short* qn = pool;                    // phase 2: 128xQS
    unsigned short* kn = pool + 128 * QS;

    const bool isbf = detect_bf16((const unsigned int*)x_raw);
    const unsigned short* xs  = isbf ? (const unsigned short*)x_raw   : xb;
    const unsigned short* qks = isbf ? (const unsigned short*)qkw_raw : qkwb;
    const unsigned short* cwb = isbf ? (const unsigned short*)cwb_raw : cwbb;

    const int t    = threadIdx.x;
    const int wave = t >> 6;
    const int lane = t & 63;
    // XCD-chunked bijective swizzle (1024 blocks, 128 per XCD)
    const int lin     = blockIdx.y * 16 + blockIdx.x;
    const int logical = (lin & 7) * 128 + (lin >> 3);
    const int h       = logical & 15;
    const int mt      = logical >> 4;       // m-tile 0..63
    const int m0      = mt * 128;
    const int K       = C_;

    // staging: wave stages rows [wave*32, wave*32+32) of each 128x64 tile,
    // 4 x async_load16 per operand (8 rows per load). Source col-unit is
    // pre-swizzled u ^= (row&7) (row&7 == (lane>>3)&7 here).
    const int srow  = lane >> 3;                    // 0..7
    const int sunit = (lane & 7) ^ srow;            // involutive swizzle
    const unsigned short* gA = xs + (size_t)(m0 + wave * 32 + srow) * K + sunit * 8;
    const int vb = wave * 32;                       // virtual B row 0..127
    const size_t brow = (vb < 64) ? (size_t)(h * HD + vb)
                                  : (size_t)(C_ + h * HD + (vb - 64));
    const unsigned short* gB = qks + (brow + srow) * K + sunit * 8;

    const int wr = (wave >> 1) * 64;        // row quadrant
    const int wc = (wave & 1) * 64;         // col quadrant: 0 = q, 64 = k
    const int lq = lane >> 4;
    const int lm = lane & 15;
    const int c0 = (lq ^ (lm & 7)) * 8;     // swizzled read col, ks=0

    f32x4 acc[4][4];
    #pragma unroll
    for (int i = 0; i < 4; ++i)
        #pragma unroll
        for (int j = 0; j < 4; ++j) acc[i][j] = 0.f;

    auto stage = [&](int buf) {
        unsigned short* dA = AsBase + buf * 8192 + wave * 2048;
        unsigned short* dB = BsBase + buf * 8192 + wave * 2048;
        #pragma unroll
        for (int i = 0; i < 4; ++i) {
            async_load16(gA + (size_t)i * 8 * K, dA + i * 512);
            async_load16(gB + (size_t)i * 8 * K, dB + i * 512);
        }
        gA += 64; gB += 64;
    };
    auto compute = [&](int buf) {
        const unsigned short* As = AsBase + buf * 8192;
        const unsigned short* Bs = BsBase + buf * 8192;
        #pragma unroll
        for (int ks = 0; ks < 2; ++ks) {
            const int cc = c0 ^ (ks * 32);
            bf16x8 af[4], bfr[4];
            #pragma unroll
            for (int i = 0; i < 4; ++i)
                af[i] = *(const bf16x8*)&As[(wr + i * 16 + lm) * 64 + cc];
            #pragma unroll
            for (int j = 0; j < 4; ++j)
                bfr[j] = *(const bf16x8*)&Bs[(wc + j * 16 + lm) * 64 + cc];
            #pragma unroll
            for (int i = 0; i < 4; ++i)
                #pragma unroll
                for (int j = 0; j < 4; ++j)
                    acc[i][j] = __builtin_amdgcn_mfma_f32_16x16x32_bf16(
                        af[i], bfr[j], acc[i][j], 0, 0, 0);
        }
    };

    constexpr int NTK = C_ / 64;   // 16 K-tiles
    stage(0);
    __syncthreads();
    for (int kt = 0; kt < NTK - 1; ++kt) {
        stage((kt + 1) & 1);       // prefetch next tile (other buffer)
        compute(kt & 1);           // 32 MFMA + 16 ds_read under the prefetch
        __syncthreads();           // drains vmcnt+lgkm: next tile ready, reads done
    }
    compute((NTK - 1) & 1);
    __syncthreads();               // before pool reuse by phase 2

    // ---- phase 2a: per-row l2 norm + scaled bf16 store to LDS ----
    unsigned short* dst = (wc == 0) ? qn : kn;
    #pragma unroll
    for (int i = 0; i < 4; ++i) {
        float inv[4];
        #pragma unroll
        for (int r = 0; r < 4; ++r) {
            float s = 0.f;
            #pragma unroll
            for (int j = 0; j < 4; ++j) s += acc[i][j][r] * acc[i][j][r];
            s += __shfl_xor(s, 1, 64);
            s += __shfl_xor(s, 2, 64);
            s += __shfl_xor(s, 4, 64);
            s += __shfl_xor(s, 8, 64);
            inv[r] = 1.f / fmaxf(sqrtf(s), 1e-12f);
        }
        #pragma unroll
        for (int j = 0; j < 4; ++j)
            #pragma unroll
            for (int r = 0; r < 4; ++r) {
                const int row = wr + i * 16 + lq * 4 + r;
                dst[row * QS + j * 16 + lm] = f2b(acc[i][j][r] * inv[r]);
            }
    }
    __syncthreads();

    // ---- phase 2b: attn = qn@We2T^T + kn@Wr2T^T + cw_b ----
    const int b  = mt >> 4;
    const int bh = b * H_ + h;
    const unsigned short* wq = we2t + (size_t)bh * HD * HD;
    const unsigned short* wk = wr2t + (size_t)bh * HD * HD;

    bf16x8 bq[2][4], bk[2][4];
    #pragma unroll
    for (int t2 = 0; t2 < 2; ++t2)
        #pragma unroll
        for (int j = 0; j < 4; ++j) {
            const int dout = j * 16 + lm;
            bq[t2][j] = *(const bf16x8*)&wq[dout * HD + t2 * 32 + lq * 8];
            bk[t2][j] = *(const bf16x8*)&wk[dout * HD + t2 * 32 + lq * 8];
        }

    f32x4 accS[2][4];
    #pragma unroll
    for (int rt = 0; rt < 2; ++rt)
        #pragma unroll
        for (int j = 0; j < 4; ++j) accS[rt][j] = 0.f;

    #pragma unroll
    for (int rt = 0; rt < 2; ++rt) {
        const int lr = wave * 32 + rt * 16 + lm;
        bf16x8 aq0 = *(const bf16x8*)&qn[lr * QS + lq * 8];
        bf16x8 aq1 = *(const bf16x8*)&qn[lr * QS + 32 + lq * 8];
        bf16x8 ak0 = *(const bf16x8*)&kn[lr * QS + lq * 8];
        bf16x8 ak1 = *(const bf16x8*)&kn[lr * QS + 32 + lq * 8];
        #pragma unroll
        for (int j = 0; j < 4; ++j) {
            accS[rt][j] = __builtin_amdgcn_mfma_f32_16x16x32_bf16(aq0, bq[0][j], accS[rt][j], 0, 0, 0);
            accS[rt][j] = __builtin_amdgcn_mfma_f32_16x16x32_bf16(aq1, bq[1][j], accS[rt][j], 0, 0, 0);
            accS[rt][j] = __builtin_amdgcn_mfma_f32_16x16x32_bf16(ak0, bk[0][j], accS[rt][j], 0, 0, 0);
            accS[rt][j] = __builtin_amdgcn_mfma_f32_16x16x32_bf16(ak1, bk[1][j], accS[rt][j], 0, 0, 0);
        }
    }

    #pragma unroll
    for (int rt = 0; rt < 2; ++rt)
        #pragma unroll
        for (int j = 0; j < 4; ++j) {
            const int dout = j * 16 + lm;
            const float bv = b2f_raw(cwb[dout]);
            #pragma unroll
            for (int r = 0; r < 4; ++r) {
                const int row = m0 + wave * 32 + rt * 16 + lq * 4 + r;
                attn[(size_t)row * C_ + h * HD + dout] = f2b(accS[rt][j][r] + bv);
            }
        }
}

// ---------------------------------------------------------------------------
// Output projection: round-4 body + inline detect + raw-pointer select +
// XCD-chunked swizzle (512 blocks, 64 per XCD: A-panels x1 per XCD).
// ---------------------------------------------------------------------------
template <bool OBF>
__device__ void mfma_gemm_body64(const unsigned short* __restrict__ A,
                                 const unsigned short* __restrict__ W,
                                 const unsigned short* __restrict__ bias,
                                 void* __restrict__ out,
                                 int M, int N, int K, int m0, int n0) {
    __shared__ __align__(16) unsigned short AsBase[16384];  // 2 x 128x64
    __shared__ __align__(16) unsigned short BsBase[16384];  // 2 x 128x64 (64 KB)

    const int t    = threadIdx.x;
    const int wave = t >> 6;
    const int lane = t & 63;

    const int srow  = lane >> 3;
    const int sunit = (lane & 7) ^ srow;
    const unsigned short* gA = A + (size_t)(m0 + wave * 32 + srow) * K + sunit * 8;
    const unsigned short* gB = W + (size_t)(n0 + wave * 32 + srow) * K + sunit * 8;

    const int wr = (wave >> 1) * 64;
    const int wc = (wave & 1) * 64;
    const int lq = lane >> 4;
    const int lm = lane & 15;
    const int c0 = (lq ^ (lm & 7)) * 8;

    f32x4 acc[4][4];
    #pragma unroll
    for (int i = 0; i < 4; ++i)
        #pragma unroll
        for (int j = 0; j < 4; ++j) acc[i][j] = 0.f;

    auto stage = [&](int buf) {
        unsigned short* dA = AsBase + buf * 8192 + wave * 2048;
        unsigned short* dB = BsBase + buf * 8192 + wave * 2048;
        #pragma unroll
        for (int i = 0; i < 4; ++i) {
            async_load16(gA + (size_t)i * 8 * K, dA + i * 512);
            async_load16(gB + (size_t)i * 8 * K, dB + i * 512);
        }
        gA += 64; gB += 64;
    };
    auto compute = [&](int buf) {
        const unsigned short* As = AsBase + buf * 8192;
        const unsigned short* Bs = BsBase + buf * 8192;
        #pragma unroll
        for (int ks = 0; ks < 2; ++ks) {
            const int cc = c0 ^ (ks * 32);
            bf16x8 af[4], bfr[4];
            #pragma unroll
            for (int i = 0; i < 4; ++i)
                af[i] = *(const bf16x8*)&As[(wr + i * 16 + lm) * 64 + cc];
            #pragma unroll
            for (int j = 0; j < 4; ++j)
                bfr[j] = *(const bf16x8*)&Bs[(wc + j * 16 + lm) * 64 + cc];
            #pragma unroll
            for (int i = 0; i < 4; ++i)
                #pragma unroll
                for (int j = 0; j < 4; ++j)
                    acc[i][j] = __builtin_amdgcn_mfma_f32_16x16x32_bf16(
                        af[i], bfr[j], acc[i][j], 0, 0, 0);
        }
    };

    const int NTK = K / 64;   // 16
    stage(0);
    __syncthreads();
    for (int kt = 0; kt < NTK - 1; ++kt) {
        stage((kt + 1) & 1);
        compute(kt & 1);
        __syncthreads();
    }
    compute((NTK - 1) & 1);
    // epilogue is register-only: no trailing barrier needed

    #pragma unroll
    for (int i = 0; i < 4; ++i) {
        #pragma unroll
        for (int j = 0; j < 4; ++j) {
            const int col = n0 + wc + j * 16 + lm;
            const float bv = b2f_raw(bias[col]);
            #pragma unroll
            for (int r = 0; r < 4; ++r) {
                const int row = m0 + wr + i * 16 + lq * 4 + r;
                const float v = acc[i][j][r] + bv;
                if constexpr (OBF)
                    ((__hip_bfloat16*)out)[(size_t)row * N + col] = __float2bfloat16(v);
                else
                    ((float*)out)[(size_t)row * N + col] = v;
            }
        }
    }
}

__global__ __launch_bounds__(256, 2)
void gemm2_kernel(const void* __restrict__ x_raw,
                  const void* __restrict__ pw_raw,
                  const void* __restrict__ pb_raw,
                  const unsigned short* __restrict__ attn,
                  const unsigned short* __restrict__ pwb,
                  const unsigned short* __restrict__ pbb,
                  void* __restrict__ out) {
    const bool isbf = detect_bf16((const unsigned int*)x_raw);
    const unsigned short* W = isbf ? (const unsigned short*)pw_raw : pwb;
    const unsigned short* bias = isbf ? (const unsigned short*)pb_raw : pbb;
    // XCD-chunked bijective swizzle (512 blocks, 64 per XCD)
    const int lin     = blockIdx.y * 8 + blockIdx.x;
    const int logical = (lin & 7) * 64 + (lin >> 3);
    const int n0      = (logical & 7) * 128;
    const int m0      = (logical >> 3) * 128;
    if (isbf) mfma_gemm_body64<true>(attn, W, bias, out, B_ * N_, C_, C_, m0, n0);
    else      mfma_gemm_body64<false>(attn, W, bias, out, B_ * N_, C_, C_, m0, n0);
}

// ---------------------------------------------------------------------------
// 4 dispatches: fused(convert+wec+gather) -> collapse -> gemm1_score -> gemm2.
// detect is inlined (deterministic, per-block). bf16 inputs take the
// zero-copy path (no x/qkw/proj_w conversion traffic).
// ws high-water ~44 MB (< proven-safe 57.9 MB).
// ---------------------------------------------------------------------------
extern "C" void kernel_launch(void* const* d_in, const int* in_sizes, int n_in,
                              void* d_out, int out_size, void* d_ws, size_t ws_size,
                              hipStream_t stream) {
    (void)in_sizes; (void)n_in; (void)out_size; (void)ws_size;

    char* ws = (char*)d_ws;
    size_t off = 0;
    auto alloc = [&](size_t bytes) {
        char* p = ws + off;
        off += (bytes + 255) & ~(size_t)255;
        return p;
    };

    unsigned short* xb    = (unsigned short*)alloc((size_t)B_ * N_ * C_ * 2);   // 16.78 MB
    unsigned short* qkwb  = (unsigned short*)alloc((size_t)2 * C_ * C_ * 2);    // 4.19 MB
    unsigned short* pwb   = (unsigned short*)alloc((size_t)C_ * C_ * 2);        // 2.10 MB
    unsigned short* pbb   = (unsigned short*)alloc((size_t)C_ * 2);
    unsigned short* cwbb  = (unsigned short*)alloc((size_t)HD * 2);
    unsigned short* attn  = (unsigned short*)alloc((size_t)B_ * N_ * C_ * 2);   // 16.78 MB
    unsigned short* we2t  = (unsigned short*)alloc((size_t)B_ * H_ * HD * HD * 2);
    unsigned short* wr2t  = (unsigned short*)alloc((size_t)B_ * H_ * HD * HD * 2);
    unsigned short* wect  = (unsigned short*)alloc((size_t)H_ * HD * RP * 2);
    unsigned short* wrct  = (unsigned short*)alloc((size_t)H_ * HD * RP * 2);
    unsigned short* xh    = (unsigned short*)alloc((size_t)B_ * H_ * HD * RP * 2);

    const int M = B_ * N_;  // 8192

    // 1) fused convert (skipped for bf16) + wec + gather
    CvtArgs ca;
    ca.src[0] = d_in[0]; ca.dst[0] = xb;   ca.size[0] = B_ * N_ * C_;
    ca.src[1] = d_in[1]; ca.dst[1] = qkwb; ca.size[1] = 2 * C_ * C_;
    ca.src[2] = d_in[2]; ca.dst[2] = pwb;  ca.size[2] = C_ * C_;
    ca.src[3] = d_in[3]; ca.dst[3] = pbb;  ca.size[3] = C_;
    ca.src[4] = d_in[7]; ca.dst[4] = cwbb; ca.size[4] = HD;
    fused_prep_kernel<<<dim3(2048, 7), 256, 0, stream>>>(
        ca, d_in[4], d_in[5], d_in[6], wect, wrct, xh);

    // 2) collapse -> We2T/Wr2T
    collapse_kernel<<<B_ * H_ * 4, 64, 0, stream>>>(xh, wect, wrct, we2t, wr2t);

    // 3) fused qk-projection + l2norm + score -> attn
    gemm1_score_kernel<<<dim3(16, M / 128), 256, 0, stream>>>(
        d_in[0], d_in[1], d_in[7], xb, qkwb, cwbb, we2t, wr2t, attn);

    // 4) output projection: out = attn @ proj_w^T + proj_b
    gemm2_kernel<<<dim3(C_ / 128, M / 128), 256, 0, stream>>>(
        d_in[0], d_in[2], d_in[3], attn, pwb, pbb, d_out);
}

// Round 6
// 206.737 us; speedup vs baseline: 1.1084x; 1.1084x over previous
//
#include <hip/hip_runtime.h>
#include <hip/hip_bf16.h>

// Problem shapes (fixed by setup_inputs)
constexpr int B_  = 4;
constexpr int N_  = 2048;
constexpr int C_  = 1024;
constexpr int H_  = 16;
constexpr int HD  = 64;    // head dim
constexpr int LR  = 20;    // low rank
constexpr int RS  = 200;   // subsample length R
constexpr int RP  = 224;   // RS padded to multiple of 32 (zero-filled)

typedef __attribute__((ext_vector_type(8))) short bf16x8;
typedef __attribute__((ext_vector_type(4))) float f32x4;

__device__ __forceinline__ float b2f_raw(unsigned short u) {
    union { unsigned int i; float f; } v;
    v.i = ((unsigned int)u) << 16;
    return v.f;
}
__device__ __forceinline__ unsigned short f2b(float f) {
    __hip_bfloat16 h = __float2bfloat16(f);
    return *(unsigned short*)&h;
}
template <bool BF>
__device__ __forceinline__ float ldg(const void* p, size_t i) {
    if constexpr (BF) return b2f_raw(((const unsigned short*)p)[i]);
    else              return ((const float*)p)[i];
}

// async 16B global->LDS (wave-uniform LDS base; HW scatters lane i at +16*i)
__device__ __forceinline__ void async_load16(const unsigned short* g, unsigned short* l) {
    __builtin_amdgcn_global_load_lds(
        (const __attribute__((address_space(1))) unsigned int*)(const void*)g,
        (__attribute__((address_space(3))) unsigned int*)(void*)l,
        16, 0, 0);
}

// ---------------------------------------------------------------------------
// Inline dtype detect (deterministic function of x[0..1023]; all blocks in
// all kernels agree). Wave-uniform; ~4KB L2-hot read.
// ---------------------------------------------------------------------------
__device__ __forceinline__ bool detect_bf16(const unsigned int* __restrict__ x) {
    const int lane = threadIdx.x & 63;
    int cnt = 0;
    #pragma unroll
    for (int i = 0; i < 16; ++i) {
        const unsigned int w = x[lane * 16 + i];
        const unsigned int e = (w >> 7) & 0xFFu;
        cnt += (e >= 103u && e <= 140u) ? 1 : 0;
    }
    #pragma unroll
    for (int s = 1; s < 64; s <<= 1) cnt += __shfl_xor(cnt, s, 64);
    return cnt > 512;
}

// ---------------------------------------------------------------------------
// Fused prep, rebalanced (round 6). Grid (2048, 3):
//  y == 0: convert x (fp32->bf16, float4; skipped when bf16)
//  y == 1: convert qkw/proj_w/proj_b/cw_b, flattened (skipped when bf16)
//  y == 2: blocks 0..895   -> wec  (wect/wrct, zero-padded r>=RS)
//          blocks 896..1023-> gather via LDS transpose (2 blocks per bh):
//            coalesced 128B reads along din, swizzled LDS [r][din^(r&31)],
//            contiguous writes along r (fixes the 64-block, 448B-stride-
//            write tail that made prep 56us in round 5's profile).
// ---------------------------------------------------------------------------
struct CvtArgs {
    const void* src[5];
    unsigned short* dst[5];
    int size[5];
};

template <bool BF>
__device__ void wec_body(const void* __restrict__ we_raw,
                         const void* __restrict__ wr_raw,
                         const void* __restrict__ cw_raw,
                         unsigned short* __restrict__ wect,
                         unsigned short* __restrict__ wrct) {
    const int o = blockIdx.x * 256 + threadIdx.x;
    if (o >= H_ * HD * RP) return;
    const int r    = o % RP;
    const int dout = (o / RP) % HD;
    const int h    = o / (RP * HD);
    float sq = 0.f, sk = 0.f;
    if (r < RS) {
        #pragma unroll
        for (int e = 0; e < LR; ++e) {
            const float cq = ldg<BF>(cw_raw, dout * 2 * LR + e);
            const float ck = ldg<BF>(cw_raw, dout * 2 * LR + LR + e);
            sq += ldg<BF>(we_raw, ((size_t)h * RS + r) * LR + e) * cq;
            sk += ldg<BF>(wr_raw, ((size_t)h * RS + r) * LR + e) * ck;
        }
    }
    wect[o] = f2b(sq);
    wrct[o] = f2b(sk);
}

template <bool BF>
__device__ void gather_lds_body(const void* __restrict__ x_raw,
                                unsigned short* __restrict__ xh,
                                unsigned short* __restrict__ sx,  // [224*32]
                                int g) {
    const int bh    = g >> 1;
    const int dhalf = g & 1;
    const int b = bh >> 4;
    const int h = bh & 15;
    const int t    = threadIdx.x;
    const int wave = t >> 6;
    const int lane = t & 63;
    const int dlo = lane & 31;
    const int rhi = lane >> 5;     // 0/1
    // fill: wave handles r = 2*rd+rhi, rd = wave..99 step 4 -> r in [0,200)
    for (int rd = wave; rd < 100; rd += 4) {
        const int r  = rd * 2 + rhi;
        const int ir = (r * (N_ - 1)) / (RS - 1);
        const size_t idx = ((size_t)b * N_ + ir) * C_ + h * HD + dhalf * 32 + dlo;
        unsigned short v;
        if constexpr (BF) v = ((const unsigned short*)x_raw)[idx];
        else              v = f2b(((const float*)x_raw)[idx]);
        sx[r * 32 + (dlo ^ (r & 31))] = v;
    }
    __syncthreads();
    // writeout: contiguous along r (512B per wave-store-iter), zero-pad r>=RS
    for (int o = t; o < 32 * 224; o += 256) {
        const int din = o / 224;   // within-half din
        const int r   = o % 224;
        const unsigned short v = (r < RS) ? sx[r * 32 + (din ^ (r & 31))]
                                          : (unsigned short)0;
        xh[(size_t)bh * HD * RP + (size_t)(dhalf * 32 + din) * RP + r] = v;
    }
}

__global__ __launch_bounds__(256)
void fused_prep_kernel(CvtArgs args,
                       const void* __restrict__ we_raw,
                       const void* __restrict__ wr_raw,
                       const void* __restrict__ cw_raw,
                       unsigned short* __restrict__ wect,
                       unsigned short* __restrict__ wrct,
                       unsigned short* __restrict__ xh) {
    __shared__ unsigned short sx[224 * 32];   // gather transpose buffer (14KB)
    const bool isbf = detect_bf16((const unsigned int*)args.src[0]);
    const int y = blockIdx.y;
    if (y == 0) {
        if (isbf) return;   // zero-copy: consumers read raw bf16 directly
        const int n4 = args.size[0] >> 2;
        const int stride = 2048 * 256;
        for (int i = blockIdx.x * 256 + threadIdx.x; i < n4; i += stride) {
            const float4 v = ((const float4*)args.src[0])[i];
            ushort4 o;
            o.x = f2b(v.x); o.y = f2b(v.y); o.z = f2b(v.z); o.w = f2b(v.w);
            ((ushort4*)args.dst[0])[i] = o;
        }
    } else if (y == 1) {
        if (isbf) return;
        const int n1 = args.size[1] >> 2;
        const int n2 = args.size[2] >> 2;
        const int n3 = args.size[3] >> 2;
        const int n4 = args.size[4] >> 2;
        const int tot = n1 + n2 + n3 + n4;
        const int stride = 2048 * 256;
        for (int i = blockIdx.x * 256 + threadIdx.x; i < tot; i += stride) {
            const float4* s; ushort4* d; int j;
            if (i < n1)                { s = (const float4*)args.src[1]; d = (ushort4*)args.dst[1]; j = i; }
            else if (i < n1 + n2)      { s = (const float4*)args.src[2]; d = (ushort4*)args.dst[2]; j = i - n1; }
            else if (i < n1 + n2 + n3) { s = (const float4*)args.src[3]; d = (ushort4*)args.dst[3]; j = i - n1 - n2; }
            else                       { s = (const float4*)args.src[4]; d = (ushort4*)args.dst[4]; j = i - n1 - n2 - n3; }
            const float4 v = s[j];
            ushort4 o;
            o.x = f2b(v.x); o.y = f2b(v.y); o.z = f2b(v.z); o.w = f2b(v.w);
            d[j] = o;
        }
    } else {
        const int blk = blockIdx.x;
        if (blk < 896) {
            if (isbf) wec_body<true>(we_raw, wr_raw, cw_raw, wect, wrct);
            else      wec_body<false>(we_raw, wr_raw, cw_raw, wect, wrct);
        } else if (blk < 1024) {
            const int g = blk - 896;
            if (isbf) gather_lds_body<true>(args.src[0], xh, sx, g);
            else      gather_lds_body<false>(args.src[0], xh, sx, g);
        }
    }
}

// ---------------------------------------------------------------------------
// collapse: We2T[bh][dout][din] = sum_r wec[h][dout][r] * xh[bh][din][r]
// Tiny NT MFMA GEMM, M=N=64, K=224. One wave per (bh, qk-sel, dout-half).
// (verified; unchanged)
// ---------------------------------------------------------------------------
__global__ __launch_bounds__(64)
void collapse_kernel(const unsigned short* __restrict__ xh,
                     const unsigned short* __restrict__ wect,
                     const unsigned short* __restrict__ wrct,
                     unsigned short* __restrict__ we2t,
                     unsigned short* __restrict__ wr2t) {
    const int blk = blockIdx.x;
    const int bh  = blk >> 2;
    const int qk  = (blk >> 1) & 1;
    const int dh  = blk & 1;
    const int h   = bh & 15;
    const int lane = threadIdx.x;
    const int lq = lane >> 4;
    const int lm = lane & 15;

    const unsigned short* wsrc = (qk ? wrct : wect) + (size_t)h * HD * RP;
    const unsigned short* xsrc = xh + (size_t)bh * HD * RP;
    unsigned short* dst = (qk ? wr2t : we2t) + (size_t)bh * HD * HD;

    f32x4 acc[2][4];
    #pragma unroll
    for (int i = 0; i < 2; ++i)
        #pragma unroll
        for (int j = 0; j < 4; ++j) acc[i][j] = 0.f;

    for (int ks = 0; ks < RP / 32; ++ks) {
        bf16x8 a[2], bfr[4];
        #pragma unroll
        for (int rt = 0; rt < 2; ++rt)
            a[rt] = *(const bf16x8*)&wsrc[(size_t)(dh * 32 + rt * 16 + lm) * RP + ks * 32 + lq * 8];
        #pragma unroll
        for (int j = 0; j < 4; ++j)
            bfr[j] = *(const bf16x8*)&xsrc[(size_t)(j * 16 + lm) * RP + ks * 32 + lq * 8];
        #pragma unroll
        for (int rt = 0; rt < 2; ++rt)
            #pragma unroll
            for (int j = 0; j < 4; ++j)
                acc[rt][j] = __builtin_amdgcn_mfma_f32_16x16x32_bf16(
                    a[rt], bfr[j], acc[rt][j], 0, 0, 0);
    }

    #pragma unroll
    for (int rt = 0; rt < 2; ++rt)
        #pragma unroll
        for (int j = 0; j < 4; ++j)
            #pragma unroll
            for (int r = 0; r < 4; ++r) {
                const int dout = dh * 32 + rt * 16 + lq * 4 + r;
                const int din  = j * 16 + lm;
                dst[dout * HD + din] = f2b(acc[rt][j][r]);
            }
}

// ---------------------------------------------------------------------------
// Fused gemm1 + l2norm + score. (unchanged from round 5 — passed)
// ---------------------------------------------------------------------------
__global__ __launch_bounds__(256, 2)
void gemm1_score_kernel(const void* __restrict__ x_raw,
                        const void* __restrict__ qkw_raw,
                        const void* __restrict__ cwb_raw,
                        const unsigned short* __restrict__ xb,
                        const unsigned short* __restrict__ qkwb,
                        const unsigned short* __restrict__ cwbb,
                        const unsigned short* __restrict__ we2t,
                        const unsigned short* __restrict__ wr2t,
                        unsigned short* __restrict__ attn) {
    constexpr int QS = 72;
    __shared__ __align__(16) unsigned short pool[32768];  // 64 KB
    unsigned short* const AsBase = pool;          // 2 x 128x64 A tiles (32 KB)
    unsigned short* const BsBase = pool + 16384;  // 2 x 128x64 B tiles (32 KB)
    unsigned short* qn = pool;                    // phase 2: 128xQS
    unsigned short* kn = pool + 128 * QS;

    const bool isbf = detect_bf16((const unsigned int*)x_raw);
    const unsigned short* xs  = isbf ? (const unsigned short*)x_raw   : xb;
    const unsigned short* qks = isbf ? (const unsigned short*)qkw_raw : qkwb;
    const unsigned short* cwb = isbf ? (const unsigned short*)cwb_raw : cwbb;

    const int t    = threadIdx.x;
    const int wave = t >> 6;
    const int lane = t & 63;
    // XCD-chunked bijective swizzle (1024 blocks, 128 per XCD)
    const int lin     = blockIdx.y * 16 + blockIdx.x;
    const int logical = (lin & 7) * 128 + (lin >> 3);
    const int h       = logical & 15;
    const int mt      = logical >> 4;       // m-tile 0..63
    const int m0      = mt * 128;
    const int K       = C_;

    const int srow  = lane >> 3;                    // 0..7
    const int sunit = (lane & 7) ^ srow;            // involutive swizzle
    const unsigned short* gA = xs + (size_t)(m0 + wave * 32 + srow) * K + sunit * 8;
    const int vb = wave * 32;                       // virtual B row 0..127
    const size_t brow = (vb < 64) ? (size_t)(h * HD + vb)
                                  : (size_t)(C_ + h * HD + (vb - 64));
    const unsigned short* gB = qks + (brow + srow) * K + sunit * 8;

    const int wr = (wave >> 1) * 64;        // row quadrant
    const int wc = (wave & 1) * 64;         // col quadrant: 0 = q, 64 = k
    const int lq = lane >> 4;
    const int lm = lane & 15;
    const int c0 = (lq ^ (lm & 7)) * 8;     // swizzled read col, ks=0

    f32x4 acc[4][4];
    #pragma unroll
    for (int i = 0; i < 4; ++i)
        #pragma unroll
        for (int j = 0; j < 4; ++j) acc[i][j] = 0.f;

    auto stage = [&](int buf) {
        unsigned short* dA = AsBase + buf * 8192 + wave * 2048;
        unsigned short* dB = BsBase + buf * 8192 + wave * 2048;
        #pragma unroll
        for (int i = 0; i < 4; ++i) {
            async_load16(gA + (size_t)i * 8 * K, dA + i * 512);
            async_load16(gB + (size_t)i * 8 * K, dB + i * 512);
        }
        gA += 64; gB += 64;
    };
    auto compute = [&](int buf) {
        const unsigned short* As = AsBase + buf * 8192;
        const unsigned short* Bs = BsBase + buf * 8192;
        #pragma unroll
        for (int ks = 0; ks < 2; ++ks) {
            const int cc = c0 ^ (ks * 32);
            bf16x8 af[4], bfr[4];
            #pragma unroll
            for (int i = 0; i < 4; ++i)
                af[i] = *(const bf16x8*)&As[(wr + i * 16 + lm) * 64 + cc];
            #pragma unroll
            for (int j = 0; j < 4; ++j)
                bfr[j] = *(const bf16x8*)&Bs[(wc + j * 16 + lm) * 64 + cc];
            #pragma unroll
            for (int i = 0; i < 4; ++i)
                #pragma unroll
                for (int j = 0; j < 4; ++j)
                    acc[i][j] = __builtin_amdgcn_mfma_f32_16x16x32_bf16(
                        af[i], bfr[j], acc[i][j], 0, 0, 0);
        }
    };

    constexpr int NTK = C_ / 64;   // 16 K-tiles
    stage(0);
    __syncthreads();
    for (int kt = 0; kt < NTK - 1; ++kt) {
        stage((kt + 1) & 1);       // prefetch next tile (other buffer)
        compute(kt & 1);           // 32 MFMA + 16 ds_read under the prefetch
        __syncthreads();           // drains vmcnt+lgkm: next tile ready, reads done
    }
    compute((NTK - 1) & 1);
    __syncthreads();               // before pool reuse by phase 2

    // ---- phase 2a: per-row l2 norm + scaled bf16 store to LDS ----
    unsigned short* dst = (wc == 0) ? qn : kn;
    #pragma unroll
    for (int i = 0; i < 4; ++i) {
        float inv[4];
        #pragma unroll
        for (int r = 0; r < 4; ++r) {
            float s = 0.f;
            #pragma unroll
            for (int j = 0; j < 4; ++j) s += acc[i][j][r] * acc[i][j][r];
            s += __shfl_xor(s, 1, 64);
            s += __shfl_xor(s, 2, 64);
            s += __shfl_xor(s, 4, 64);
            s += __shfl_xor(s, 8, 64);
            inv[r] = 1.f / fmaxf(sqrtf(s), 1e-12f);
        }
        #pragma unroll
        for (int j = 0; j < 4; ++j)
            #pragma unroll
            for (int r = 0; r < 4; ++r) {
                const int row = wr + i * 16 + lq * 4 + r;
                dst[row * QS + j * 16 + lm] = f2b(acc[i][j][r] * inv[r]);
            }
    }
    __syncthreads();

    // ---- phase 2b: attn = qn@We2T^T + kn@Wr2T^T + cw_b ----
    const int b  = mt >> 4;
    const int bh = b * H_ + h;
    const unsigned short* wq = we2t + (size_t)bh * HD * HD;
    const unsigned short* wk = wr2t + (size_t)bh * HD * HD;

    bf16x8 bq[2][4], bk[2][4];
    #pragma unroll
    for (int t2 = 0; t2 < 2; ++t2)
        #pragma unroll
        for (int j = 0; j < 4; ++j) {
            const int dout = j * 16 + lm;
            bq[t2][j] = *(const bf16x8*)&wq[dout * HD + t2 * 32 + lq * 8];
            bk[t2][j] = *(const bf16x8*)&wk[dout * HD + t2 * 32 + lq * 8];
        }

    f32x4 accS[2][4];
    #pragma unroll
    for (int rt = 0; rt < 2; ++rt)
        #pragma unroll
        for (int j = 0; j < 4; ++j) accS[rt][j] = 0.f;

    #pragma unroll
    for (int rt = 0; rt < 2; ++rt) {
        const int lr = wave * 32 + rt * 16 + lm;
        bf16x8 aq0 = *(const bf16x8*)&qn[lr * QS + lq * 8];
        bf16x8 aq1 = *(const bf16x8*)&qn[lr * QS + 32 + lq * 8];
        bf16x8 ak0 = *(const bf16x8*)&kn[lr * QS + lq * 8];
        bf16x8 ak1 = *(const bf16x8*)&kn[lr * QS + 32 + lq * 8];
        #pragma unroll
        for (int j = 0; j < 4; ++j) {
            accS[rt][j] = __builtin_amdgcn_mfma_f32_16x16x32_bf16(aq0, bq[0][j], accS[rt][j], 0, 0, 0);
            accS[rt][j] = __builtin_amdgcn_mfma_f32_16x16x32_bf16(aq1, bq[1][j], accS[rt][j], 0, 0, 0);
            accS[rt][j] = __builtin_amdgcn_mfma_f32_16x16x32_bf16(ak0, bk[0][j], accS[rt][j], 0, 0, 0);
            accS[rt][j] = __builtin_amdgcn_mfma_f32_16x16x32_bf16(ak1, bk[1][j], accS[rt][j], 0, 0, 0);
        }
    }

    #pragma unroll
    for (int rt = 0; rt < 2; ++rt)
        #pragma unroll
        for (int j = 0; j < 4; ++j) {
            const int dout = j * 16 + lm;
            const float bv = b2f_raw(cwb[dout]);
            #pragma unroll
            for (int r = 0; r < 4; ++r) {
                const int row = m0 + wave * 32 + rt * 16 + lq * 4 + r;
                attn[(size_t)row * C_ + h * HD + dout] = f2b(accS[rt][j][r] + bv);
            }
        }
}

// ---------------------------------------------------------------------------
// Output projection. (unchanged from round 5 — passed)
// ---------------------------------------------------------------------------
template <bool OBF>
__device__ void mfma_gemm_body64(const unsigned short* __restrict__ A,
                                 const unsigned short* __restrict__ W,
                                 const unsigned short* __restrict__ bias,
                                 void* __restrict__ out,
                                 int M, int N, int K, int m0, int n0) {
    __shared__ __align__(16) unsigned short AsBase[16384];  // 2 x 128x64
    __shared__ __align__(16) unsigned short BsBase[16384];  // 2 x 128x64 (64 KB)

    const int t    = threadIdx.x;
    const int wave = t >> 6;
    const int lane = t & 63;

    const int srow  = lane >> 3;
    const int sunit = (lane & 7) ^ srow;
    const unsigned short* gA = A + (size_t)(m0 + wave * 32 + srow) * K + sunit * 8;
    const unsigned short* gB = W + (size_t)(n0 + wave * 32 + srow) * K + sunit * 8;

    const int wr = (wave >> 1) * 64;
    const int wc = (wave & 1) * 64;
    const int lq = lane >> 4;
    const int lm = lane & 15;
    const int c0 = (lq ^ (lm & 7)) * 8;

    f32x4 acc[4][4];
    #pragma unroll
    for (int i = 0; i < 4; ++i)
        #pragma unroll
        for (int j = 0; j < 4; ++j) acc[i][j] = 0.f;

    auto stage = [&](int buf) {
        unsigned short* dA = AsBase + buf * 8192 + wave * 2048;
        unsigned short* dB = BsBase + buf * 8192 + wave * 2048;
        #pragma unroll
        for (int i = 0; i < 4; ++i) {
            async_load16(gA + (size_t)i * 8 * K, dA + i * 512);
            async_load16(gB + (size_t)i * 8 * K, dB + i * 512);
        }
        gA += 64; gB += 64;
    };
    auto compute = [&](int buf) {
        const unsigned short* As = AsBase + buf * 8192;
        const unsigned short* Bs = BsBase + buf * 8192;
        #pragma unroll
        for (int ks = 0; ks < 2; ++ks) {
            const int cc = c0 ^ (ks * 32);
            bf16x8 af[4], bfr[4];
            #pragma unroll
            for (int i = 0; i < 4; ++i)
                af[i] = *(const bf16x8*)&As[(wr + i * 16 + lm) * 64 + cc];
            #pragma unroll
            for (int j = 0; j < 4; ++j)
                bfr[j] = *(const bf16x8*)&Bs[(wc + j * 16 + lm) * 64 + cc];
            #pragma unroll
            for (int i = 0; i < 4; ++i)
                #pragma unroll
                for (int j = 0; j < 4; ++j)
                    acc[i][j] = __builtin_amdgcn_mfma_f32_16x16x32_bf16(
                        af[i], bfr[j], acc[i][j], 0, 0, 0);
        }
    };

    const int NTK = K / 64;   // 16
    stage(0);
    __syncthreads();
    for (int kt = 0; kt < NTK - 1; ++kt) {
        stage((kt + 1) & 1);
        compute(kt & 1);
        __syncthreads();
    }
    compute((NTK - 1) & 1);
    // epilogue is register-only: no trailing barrier needed

    #pragma unroll
    for (int i = 0; i < 4; ++i) {
        #pragma unroll
        for (int j = 0; j < 4; ++j) {
            const int col = n0 + wc + j * 16 + lm;
            const float bv = b2f_raw(bias[col]);
            #pragma unroll
            for (int r = 0; r < 4; ++r) {
                const int row = m0 + wr + i * 16 + lq * 4 + r;
                const float v = acc[i][j][r] + bv;
                if constexpr (OBF)
                    ((__hip_bfloat16*)out)[(size_t)row * N + col] = __float2bfloat16(v);
                else
                    ((float*)out)[(size_t)row * N + col] = v;
            }
        }
    }
}

__global__ __launch_bounds__(256, 2)
void gemm2_kernel(const void* __restrict__ x_raw,
                  const void* __restrict__ pw_raw,
                  const void* __restrict__ pb_raw,
                  const unsigned short* __restrict__ attn,
                  const unsigned short* __restrict__ pwb,
                  const unsigned short* __restrict__ pbb,
                  void* __restrict__ out) {
    const bool isbf = detect_bf16((const unsigned int*)x_raw);
    const unsigned short* W = isbf ? (const unsigned short*)pw_raw : pwb;
    const unsigned short* bias = isbf ? (const unsigned short*)pb_raw : pbb;
    // XCD-chunked bijective swizzle (512 blocks, 64 per XCD)
    const int lin     = blockIdx.y * 8 + blockIdx.x;
    const int logical = (lin & 7) * 64 + (lin >> 3);
    const int n0      = (logical & 7) * 128;
    const int m0      = (logical >> 3) * 128;
    if (isbf) mfma_gemm_body64<true>(attn, W, bias, out, B_ * N_, C_, C_, m0, n0);
    else      mfma_gemm_body64<false>(attn, W, bias, out, B_ * N_, C_, C_, m0, n0);
}

// ---------------------------------------------------------------------------
// 4 dispatches: prep(convert+wec+gather) -> collapse -> gemm1_score -> gemm2.
// ws high-water ~44 MB (< proven-safe 57.9 MB).
// ---------------------------------------------------------------------------
extern "C" void kernel_launch(void* const* d_in, const int* in_sizes, int n_in,
                              void* d_out, int out_size, void* d_ws, size_t ws_size,
                              hipStream_t stream) {
    (void)in_sizes; (void)n_in; (void)out_size; (void)ws_size;

    char* ws = (char*)d_ws;
    size_t off = 0;
    auto alloc = [&](size_t bytes) {
        char* p = ws + off;
        off += (bytes + 255) & ~(size_t)255;
        return p;
    };

    unsigned short* xb    = (unsigned short*)alloc((size_t)B_ * N_ * C_ * 2);   // 16.78 MB
    unsigned short* qkwb  = (unsigned short*)alloc((size_t)2 * C_ * C_ * 2);    // 4.19 MB
    unsigned short* pwb   = (unsigned short*)alloc((size_t)C_ * C_ * 2);        // 2.10 MB
    unsigned short* pbb   = (unsigned short*)alloc((size_t)C_ * 2);
    unsigned short* cwbb  = (unsigned short*)alloc((size_t)HD * 2);
    unsigned short* attn  = (unsigned short*)alloc((size_t)B_ * N_ * C_ * 2);   // 16.78 MB
    unsigned short* we2t  = (unsigned short*)alloc((size_t)B_ * H_ * HD * HD * 2);
    unsigned short* wr2t  = (unsigned short*)alloc((size_t)B_ * H_ * HD * HD * 2);
    unsigned short* wect  = (unsigned short*)alloc((size_t)H_ * HD * RP * 2);
    unsigned short* wrct  = (unsigned short*)alloc((size_t)H_ * HD * RP * 2);
    unsigned short* xh    = (unsigned short*)alloc((size_t)B_ * H_ * HD * RP * 2);

    const int M = B_ * N_;  // 8192

    // 1) prep: converts (skipped for bf16) + wec + gather
    CvtArgs ca;
    ca.src[0] = d_in[0]; ca.dst[0] = xb;   ca.size[0] = B_ * N_ * C_;
    ca.src[1] = d_in[1]; ca.dst[1] = qkwb; ca.size[1] = 2 * C_ * C_;
    ca.src[2] = d_in[2]; ca.dst[2] = pwb;  ca.size[2] = C_ * C_;
    ca.src[3] = d_in[3]; ca.dst[3] = pbb;  ca.size[3] = C_;
    ca.src[4] = d_in[7]; ca.dst[4] = cwbb; ca.size[4] = HD;
    fused_prep_kernel<<<dim3(2048, 3), 256, 0, stream>>>(
        ca, d_in[4], d_in[5], d_in[6], wect, wrct, xh);

    // 2) collapse -> We2T/Wr2T
    collapse_kernel<<<B_ * H_ * 4, 64, 0, stream>>>(xh, wect, wrct, we2t, wr2t);

    // 3) fused qk-projection + l2norm + score -> attn
    gemm1_score_kernel<<<dim3(16, M / 128), 256, 0, stream>>>(
        d_in[0], d_in[1], d_in[7], xb, qkwb, cwbb, we2t, wr2t, attn);

    // 4) output projection: out = attn @ proj_w^T + proj_b
    gemm2_kernel<<<dim3(C_ / 128, M / 128), 256, 0, stream>>>(
        d_in[0], d_in[2], d_in[3], attn, pwb, pbb, d_out);
}